// Round 7
// baseline (1367.326 us; speedup 1.0000x reference)
//
#include <hip/hip_runtime.h>

#define BB 64
#define TT 2048
#define II 64
#define HH 256
#define PSTR 17  // part row stride (floats): odd -> conflict-free post-loop

typedef __fp16 h2_t __attribute__((ext_vector_type(2)));
typedef __fp16 h8_t __attribute__((ext_vector_type(8)));

#define H2(i) __builtin_bit_cast(h2_t, (i))
#define I32(h) __builtin_bit_cast(int, (h))

#if __has_builtin(__builtin_amdgcn_fdot2)
#define FDOT2(a, b, c) __builtin_amdgcn_fdot2((a), (b), (c), false)
#else
__device__ __forceinline__ float FDOT2(h2_t a, h2_t b, float c) {
    return fmaf((float)a[0], (float)b[0], fmaf((float)a[1], (float)b[1], c));
}
#endif

__device__ __forceinline__ float ftanh(float x) {
    float e = __expf(2.0f * x);
    return 1.0f - 2.0f * __builtin_amdgcn_rcpf(e + 1.0f);
}

// 0xB1 = quad_perm xor1, 0x4E = quad_perm xor2
// 0x141 = ROW_HALF_MIRROR (^7 == ^4 when bits0-1 uniform)
// 0x140 = ROW_MIRROR      (^15 == ^8 when bits0-2 uniform)
template <int CTRL>
__device__ __forceinline__ float dpp_add(float v) {
    int s = __builtin_amdgcn_update_dpp(0, __float_as_int(v), CTRL, 0xF, 0xF, true);
    return v + __int_as_float(s);
}
template <int CTRL>
__device__ __forceinline__ float dpp_get(float v) {
    int s = __builtin_amdgcn_update_dpp(0, __float_as_int(v), CTRL, 0xF, 0xF, true);
    return __int_as_float(s);
}
template <int PAT>  // 0x101F = xor4, 0x401F = xor16 (BitMode, and=0x1F)
__device__ __forceinline__ float swz_get(float v) {
    return __int_as_float(__builtin_amdgcn_ds_swizzle(__float_as_int(v), PAT));
}
template <int PAT>
__device__ __forceinline__ float swz_add(float v) { return v + swz_get<PAT>(v); }

// merge-reduce: select the value this lane keeps, add partner's contribution.
__device__ __forceinline__ float mrg4(float a, float b, int lane) {
    float t = (lane & 4) ? b : a;
    float u = (lane & 4) ? a : b;
    return t + swz_get<0x101F>(u);
}
__device__ __forceinline__ float mrg2(float a, float b, int lane) {
    float t = (lane & 2) ? b : a;
    float u = (lane & 2) ? a : b;
    return t + dpp_get<0x4E>(u);
}

// 512 threads = 8 waves, 2 waves/SIMD: sibling wave hides LDS/swizzle latency
// (R6 ran 1 wave/SIMD -> every stall was naked; 57% on-CU VALUBusy, 40% stall).
// 2 waves/EU -> 256-VGPR cap; pinned weight tile is 80 regs -> resident.
__launch_bounds__(512, 2)
__global__ void rnn_fused(const float* __restrict__ x,
                          const float* __restrict__ W_ih,
                          const float* __restrict__ W_hh,
                          const float* __restrict__ b_ih,
                          const float* __restrict__ b_hh,
                          const float* __restrict__ W_fc,
                          const float* __restrict__ b_fc,
                          float* __restrict__ out) {
    // h fp16 double-buffered; 32-half chunks at 80 B stride: chunk q, word jv
    // hits bank quad (20q+4jv)%32 -> disjoint across q -> conflict-free b128.
    __shared__ __align__(16) __fp16 hbuf[2][320];
    __shared__ float part[TT * PSTR];  // per-step head partials, read post-loop

    const int tid  = threadIdx.x;
    const int b    = blockIdx.x;
    const int lane = tid & 63;
    const int w    = tid >> 6;   // wave 0..7
    const int o    = lane >> 3;  // row group 0..7
    const int q    = lane & 7;   // k-slice 0..7

    // thread computes rows t_r = w*32 + o*4 + r (r=0..3), cols [q*32,q*32+32)
    int whh_i[4][16];  // 64 VGPRs (fp16 pairs as int)
    int wih_i[4][4];   // 16 VGPRs
#pragma unroll
    for (int r = 0; r < 4; ++r) {
        const int t_r = w * 32 + o * 4 + r;
        const float4* wr = (const float4*)(W_hh + t_r * HH + q * 32);
#pragma unroll
        for (int jv = 0; jv < 8; ++jv) {
            const float4 wv = wr[jv];
            whh_i[r][jv * 2 + 0] = I32(__builtin_amdgcn_cvt_pkrtz(wv.x, wv.y));
            whh_i[r][jv * 2 + 1] = I32(__builtin_amdgcn_cvt_pkrtz(wv.z, wv.w));
        }
        const float4* wi = (const float4*)(W_ih + t_r * II + q * 8);
        const float4 wa = wi[0], wb = wi[1];
        wih_i[r][0] = I32(__builtin_amdgcn_cvt_pkrtz(wa.x, wa.y));
        wih_i[r][1] = I32(__builtin_amdgcn_cvt_pkrtz(wa.z, wa.w));
        wih_i[r][2] = I32(__builtin_amdgcn_cvt_pkrtz(wb.x, wb.y));
        wih_i[r][3] = I32(__builtin_amdgcn_cvt_pkrtz(wb.z, wb.w));
    }
    // pin weights in VGPRs: asm def can't be rematerialized/sunk (R6 lesson)
#pragma unroll
    for (int j = 0; j < 64; ++j) asm volatile("" : "+v"(((int*)whh_i)[j]));
#pragma unroll
    for (int j = 0; j < 16; ++j) asm volatile("" : "+v"(((int*)wih_i)[j]));

    // after merge-reduce, lanes l and l^1 both own row:
    const int myrow = w * 32 + o * 4 + ((lane >> 1) & 3);
    const float bias = b_ih[myrow] + b_hh[myrow];
    const float wfc  = W_fc[myrow] * 0.5f;  // pre-halved: rows duplicated x2
    const float bfc  = b_fc[0];

    for (int idx = tid; idx < 2 * 320; idx += 512) ((__fp16*)hbuf)[idx] = (__fp16)0.0f;
    __syncthreads();

    const float* xbase = x + (size_t)b * TT * II + q * 8;
    float* outb = out + (size_t)b * TT;

    // h write: even lanes, row myrow -> chunk myrow>>5 (=w), half myrow&31
    const int hoff = (myrow >> 5) * 80 + (myrow & 31) * 2;  // bytes
    __fp16* hw0 = (__fp16*)((char*)&hbuf[0][0] + hoff);
    __fp16* hw1 = (__fp16*)((char*)&hbuf[1][0] + hoff);

    // preload + convert x row 0
    h2_t xc[4];
    {
        const float4* xp = (const float4*)(xbase);
        const float4 a = xp[0], c = xp[1];
        xc[0] = __builtin_amdgcn_cvt_pkrtz(a.x, a.y);
        xc[1] = __builtin_amdgcn_cvt_pkrtz(a.z, a.w);
        xc[2] = __builtin_amdgcn_cvt_pkrtz(c.x, c.y);
        xc[3] = __builtin_amdgcn_cvt_pkrtz(c.z, c.w);
    }

    int p = 0;
    for (int i = 0; i < TT; ++i) {
        // prefetch x row i+1 (converted after the dot chain)
        const int rown = (i + 1 < TT) ? (i + 1) : (TT - 1);
        const float4* xpn = (const float4*)(xbase + rown * II);
        const float4 xna = xpn[0], xnc = xpn[1];

        // ---- dots: 4 rows x 32-col slice + 8-col input proj (80 dot2) ----
        float a0 = 0, a1 = 0, a2 = 0, a3 = 0;
        const h8_t* hp = (const h8_t*)((const char*)&hbuf[p][0] + q * 80);
#pragma unroll
        for (int jv = 0; jv < 4; ++jv) {
            const h8_t hv = hp[jv];
#pragma unroll
            for (int e = 0; e < 4; ++e) {
                const h2_t he = (e == 0) ? __builtin_shufflevector(hv, hv, 0, 1)
                              : (e == 1) ? __builtin_shufflevector(hv, hv, 2, 3)
                              : (e == 2) ? __builtin_shufflevector(hv, hv, 4, 5)
                                         : __builtin_shufflevector(hv, hv, 6, 7);
                const int j = jv * 4 + e;
                a0 = FDOT2(H2(whh_i[0][j]), he, a0);
                a1 = FDOT2(H2(whh_i[1][j]), he, a1);
                a2 = FDOT2(H2(whh_i[2][j]), he, a2);
                a3 = FDOT2(H2(whh_i[3][j]), he, a3);
            }
        }
#pragma unroll
        for (int e = 0; e < 4; ++e) {
            a0 = FDOT2(H2(wih_i[0][e]), xc[e], a0);
            a1 = FDOT2(H2(wih_i[1][e]), xc[e], a1);
            a2 = FDOT2(H2(wih_i[2][e]), xc[e], a2);
            a3 = FDOT2(H2(wih_i[3][e]), xc[e], a3);
        }

        // convert prefetched x (loads landed under the dot chain)
        xc[0] = __builtin_amdgcn_cvt_pkrtz(xna.x, xna.y);
        xc[1] = __builtin_amdgcn_cvt_pkrtz(xna.z, xna.w);
        xc[2] = __builtin_amdgcn_cvt_pkrtz(xnc.x, xnc.y);
        xc[3] = __builtin_amdgcn_cvt_pkrtz(xnc.z, xnc.w);

        // ---- merge-reduce over 8 k-slices; lane pair ends owning myrow ----
        const float A0 = mrg4(a0, a2, lane);   // keep rows {0,1} or {2,3}
        const float A1 = mrg4(a1, a3, lane);
        const float B0 = mrg2(A0, A1, lane);   // keep row +0 or +1
        const float C0 = dpp_add<0xB1>(B0);    // final k-bit; dup across pair

        const float hn = ftanh(C0 + bias);
        const int pn = p ^ 1;
        if (!(lane & 1)) { if (pn) hw1[0] = (__fp16)hn; else hw0[0] = (__fp16)hn; }

        // head partial (read only post-loop): 4 DPP + 1 swizzle, 2 per wave
        float c = hn * wfc;
        c = dpp_add<0xB1>(c);
        c = dpp_add<0x4E>(c);
        c = dpp_add<0x141>(c);   // ^4
        c = dpp_add<0x140>(c);   // ^8
        c = swz_add<0x401F>(c);  // ^16
        if ((lane & 31) == 0) part[i * PSTR + w * 2 + (lane >> 5)] = c;

        __syncthreads();  // ONE barrier: h_{i+1} (+part) visible
        p = pn;
    }

    // ---- deferred output head: out[b][i] = sum(part[i][0..15]) + bfc ----
    for (int i = tid; i < TT; i += 512) {
        const float* pp = &part[i * PSTR];
        float s = bfc;
#pragma unroll
        for (int k = 0; k < 16; ++k) s += pp[k];
        outb[i] = s;
    }
}

extern "C" void kernel_launch(void* const* d_in, const int* in_sizes, int n_in,
                              void* d_out, int out_size, void* d_ws, size_t ws_size,
                              hipStream_t stream) {
    const float* x    = (const float*)d_in[0];
    const float* W_ih = (const float*)d_in[1];
    const float* W_hh = (const float*)d_in[2];
    const float* b_ih = (const float*)d_in[3];
    const float* b_hh = (const float*)d_in[4];
    const float* W_fc = (const float*)d_in[5];
    const float* b_fc = (const float*)d_in[6];
    float* out = (float*)d_out;

    rnn_fused<<<BB, 512, 0, stream>>>(x, W_ih, W_hh, b_ih, b_hh, W_fc, b_fc, out);
}